// Round 1
// baseline (2473.110 us; speedup 1.0000x reference)
//
#include <hip/hip_runtime.h>

#define NN 100000
#define EE 1600000
#define EPS 1e-5f

// ---------------- fill zero (float4 grid-stride) ----------------
__global__ void fill0(float4* __restrict__ p, long n4) {
    long i = (long)blockIdx.x * blockDim.x + threadIdx.x;
    long stride = (long)gridDim.x * blockDim.x;
    float4 z = make_float4(0.f, 0.f, 0.f, 0.f);
    for (; i < n4; i += stride) p[i] = z;
}

// ---------------- k1: x1 = X@W1_1, y1 = x1@V1 (wave per node) ----------------
__global__ __launch_bounds__(256) void k1(const float* __restrict__ X,
                                          const float* __restrict__ W1,
                                          const float* __restrict__ V1,
                                          float* __restrict__ x1,
                                          float* __restrict__ y1) {
    __shared__ float Ws[128 * 16];
    __shared__ float Vs[16 * 16];
    __shared__ float Xs[4][4][132];   // wave, b, c (+4 pad: kill 4-way bank conflict)
    __shared__ float x1s[4][4][16];
    int t = threadIdx.x;
    for (int i = t; i < 2048; i += 256) Ws[i] = W1[i];
    Vs[t < 256 ? t : 0] = V1[t < 256 ? t : 0];
    int w = t >> 6, lane = t & 63;
    int n = blockIdx.x * 4 + w;
    if (n < NN) {
        for (int bb = 0; bb < 2; ++bb) {
            int b = bb * 2 + (lane >> 5);
            int c4 = (lane & 31) * 4;
            float4 v = *reinterpret_cast<const float4*>(&X[((long)b * NN + n) * 128 + c4]);
            *reinterpret_cast<float4*>(&Xs[w][b][c4]) = v;
        }
    }
    __syncthreads();
    int b = lane >> 4, h = lane & 15;
    float acc = 0.f;
    if (n < NN) {
#pragma unroll 8
        for (int c = 0; c < 128; ++c) acc += Xs[w][b][c] * Ws[c * 16 + h];
        x1s[w][b][h] = acc;
    }
    __syncthreads();
    if (n < NN) {
        float yv = 0.f;
#pragma unroll
        for (int k = 0; k < 16; ++k) yv += x1s[w][b][k] * Vs[k * 16 + h];
        x1[(long)n * 64 + lane] = acc;
        y1[(long)n * 64 + lane] = yv;
    }
}

// ---------------- scat1: wave per edge, 64 channels ----------------
__global__ __launch_bounds__(256) void scat1(const int* __restrict__ ei,
                                             const float* __restrict__ ew,
                                             const float* __restrict__ y1,
                                             float* __restrict__ agg,
                                             float* __restrict__ cnt) {
    int w = threadIdx.x >> 6, lane = threadIdx.x & 63;
    long e = (long)blockIdx.x * 4 + w;
    if (e >= EE) return;
    int src = ei[e];
    int dst = ei[EE + e];
    float wt = ew[e];
    float v = wt * y1[(long)src * 64 + lane];
    atomicAdd(&agg[(long)dst * 64 + lane], v);
    if (lane == 0) atomicAdd(&cnt[dst], 1.0f);
}

// ---------------- k3: layer1 epilogue + x2 = h1@W1_2, y2 = x2@V2 ----------------
__global__ __launch_bounds__(256) void k3(const float* __restrict__ x1,
                                          const float* __restrict__ agg1,
                                          const float* __restrict__ cnt1,
                                          const float* __restrict__ W2_1,
                                          const float* __restrict__ U1,
                                          const float* __restrict__ W1_2,
                                          const float* __restrict__ V2,
                                          float* __restrict__ x2,
                                          float* __restrict__ y2) {
    __shared__ float V2s[64 * 64];
    __shared__ float W12s[16 * 64];
    __shared__ float U1s[256];
    __shared__ float W21s[16];
    __shared__ float x1s[64];
    __shared__ float h1s[64];
    __shared__ float x2s[256];
    int t = threadIdx.x;
    int n = blockIdx.x;
    for (int i = t; i < 4096; i += 256) V2s[i] = V2[i];
    for (int i = t; i < 1024; i += 256) W12s[i] = W1_2[i];
    U1s[t] = U1[t];
    if (t < 16) W21s[t] = W2_1[t];
    if (t < 64) x1s[t] = x1[(long)n * 64 + t];
    __syncthreads();
    if (t < 64) {
        int b = t >> 4, h = t & 15;
        float xu = 0.f;
#pragma unroll
        for (int k = 0; k < 16; ++k) xu += x1s[b * 16 + k] * U1s[k * 16 + h];
        float c = fmaxf(cnt1[n], 1.f);
        float a = xu + W21s[h] * agg1[(long)n * 64 + t] / c;
        float s = a, s2 = a * a;
#pragma unroll
        for (int off = 32; off >= 1; off >>= 1) {
            s += __shfl_xor(s, off, 64);
            s2 += __shfl_xor(s2, off, 64);
        }
        float mean = s * (1.f / 64.f);
        float var = s2 * (1.f / 64.f) - mean * mean;
        float norm = (a - mean) * rsqrtf(var + EPS);
        h1s[t] = x1s[t] + fmaxf(norm, 0.f);
    }
    __syncthreads();
    int b = t >> 6, j = t & 63;
    float xv = 0.f;
#pragma unroll
    for (int h = 0; h < 16; ++h) xv += h1s[b * 16 + h] * W12s[h * 64 + j];
    x2s[t] = xv;
    x2[(long)n * 256 + t] = xv;
    __syncthreads();
    float yv = 0.f;
#pragma unroll 8
    for (int k = 0; k < 64; ++k) yv += x2s[b * 64 + k] * V2s[k * 64 + j];
    y2[(long)n * 256 + t] = yv;
}

// ---------------- scat2: wave per edge, 256 channels (4 chunks) ----------------
__global__ __launch_bounds__(256) void scat2(const int* __restrict__ ei,
                                             const float* __restrict__ ew,
                                             const float* __restrict__ y2,
                                             float* __restrict__ agg,
                                             float* __restrict__ cnt) {
    int w = threadIdx.x >> 6, lane = threadIdx.x & 63;
    long e = (long)blockIdx.x * 4 + w;
    if (e >= EE) return;
    int src = ei[e];
    int dst = ei[EE + e];
    float wt = ew[e];
    const float* ys = &y2[(long)src * 256];
    float* ad = &agg[(long)dst * 256];
#pragma unroll
    for (int c0 = 0; c0 < 256; c0 += 64) {
        atomicAdd(&ad[c0 + lane], wt * ys[c0 + lane]);
    }
    if (lane == 0) atomicAdd(&cnt[dst], 1.0f);
}

// ---------------- k5: layer2 epilogue, write (B,N,64) output ----------------
__global__ __launch_bounds__(256) void k5(const float* __restrict__ x2,
                                          const float* __restrict__ agg2,
                                          const float* __restrict__ cnt2,
                                          const float* __restrict__ W2_2,
                                          const float* __restrict__ U2,
                                          float* __restrict__ out) {
    __shared__ float U2s[4096];
    __shared__ float x2s[256];
    __shared__ float W22s[64];
    __shared__ float red[16];
    int t = threadIdx.x, n = blockIdx.x;
    for (int i = t; i < 4096; i += 256) U2s[i] = U2[i];
    if (t < 64) W22s[t] = W2_2[t];
    float xv = x2[(long)n * 256 + t];
    x2s[t] = xv;
    __syncthreads();
    int b = t >> 6, j = t & 63;
    float xu = 0.f;
#pragma unroll 8
    for (int k = 0; k < 64; ++k) xu += x2s[b * 64 + k] * U2s[k * 64 + j];
    float c = fmaxf(cnt2[n], 1.f);
    float a = xu + W22s[j] * agg2[(long)n * 256 + t] / c;
    float s = a, s2 = a * a;
#pragma unroll
    for (int off = 32; off >= 1; off >>= 1) {
        s += __shfl_xor(s, off, 64);
        s2 += __shfl_xor(s2, off, 64);
    }
    int wv = t >> 6, lane = t & 63;
    if (lane == 0) { red[wv] = s; red[8 + wv] = s2; }
    __syncthreads();
    float S = red[0] + red[1] + red[2] + red[3];
    float S2 = red[8] + red[9] + red[10] + red[11];
    float mean = S * (1.f / 256.f);
    float var = S2 * (1.f / 256.f) - mean * mean;
    float norm = (a - mean) * rsqrtf(var + EPS);
    out[((long)b * NN + n) * 64 + j] = xv + fmaxf(norm, 0.f);
}

extern "C" void kernel_launch(void* const* d_in, const int* in_sizes, int n_in,
                              void* d_out, int out_size, void* d_ws, size_t ws_size,
                              hipStream_t stream) {
    const float* X    = (const float*)d_in[0];
    const int*   ei0  = (const int*)d_in[1];
    const float* ew0  = (const float*)d_in[2];
    const int*   ei1  = (const int*)d_in[3];
    const float* ew1  = (const float*)d_in[4];
    const float* W1_1 = (const float*)d_in[8];
    const float* W2_1 = (const float*)d_in[9];
    const float* U1   = (const float*)d_in[10];
    const float* V1   = (const float*)d_in[11];
    const float* W1_2 = (const float*)d_in[12];
    const float* W2_2 = (const float*)d_in[13];
    const float* U2   = (const float*)d_in[14];
    const float* V2   = (const float*)d_in[15];
    float* out = (float*)d_out;
    char* ws = (char*)d_ws;

    // layout (bytes):
    // [0, 102.4M): region A — layer1 x1/y1/agg1/cnt1, later overlaid by agg2
    // [102.4M, 204.8M): x2   [204.8M, 307.2M): y2   [307.2M, 307.6M): cnt2
    float* x1   = (float*)(ws + 0L);
    float* y1   = (float*)(ws + 25600000L);
    float* agg1 = (float*)(ws + 51200000L);
    float* cnt1 = (float*)(ws + 76800000L);
    float* agg2 = (float*)(ws + 0L);
    float* x2   = (float*)(ws + 102400000L);
    float* y2   = (float*)(ws + 204800000L);
    float* cnt2 = (float*)(ws + 307200000L);

    // zero agg1 + cnt1 (contiguous range)
    fill0<<<2048, 256, 0, stream>>>((float4*)agg1, (25600000L + 400000L) / 16);
    k1<<<25000, 256, 0, stream>>>(X, W1_1, V1, x1, y1);
    scat1<<<400000, 256, 0, stream>>>(ei0, ew0, y1, agg1, cnt1);
    k3<<<100000, 256, 0, stream>>>(x1, agg1, cnt1, W2_1, U1, W1_2, V2, x2, y2);
    // layer1 temporaries dead; overlay agg2 on region A
    fill0<<<2048, 256, 0, stream>>>((float4*)agg2, 102400000L / 16);
    fill0<<<64, 256, 0, stream>>>((float4*)cnt2, 400000L / 16);
    scat2<<<400000, 256, 0, stream>>>(ei1, ew1, y2, agg2, cnt2);
    k5<<<100000, 256, 0, stream>>>(x2, agg2, cnt2, W2_2, U2, out);
}

// Round 2
// 1277.630 us; speedup vs baseline: 1.9357x; 1.9357x over previous
//
#include <hip/hip_runtime.h>

#define NN 100000
#define EE 1600000
#define EPS 1e-5f

// ---------------- fill zero (float4 grid-stride) ----------------
__global__ void fill0(float4* __restrict__ p, long n4) {
    long i = (long)blockIdx.x * blockDim.x + threadIdx.x;
    long stride = (long)gridDim.x * blockDim.x;
    float4 z = make_float4(0.f, 0.f, 0.f, 0.f);
    for (; i < n4; i += stride) p[i] = z;
}

// ---------------- hist: degree count for both edge lists ----------------
__global__ void hist(const int* __restrict__ ei0, const int* __restrict__ ei1,
                     int* __restrict__ deg0, int* __restrict__ deg1) {
    long i = (long)blockIdx.x * blockDim.x + threadIdx.x;
    long stride = (long)gridDim.x * blockDim.x;
    for (; i < EE; i += stride) {
        atomicAdd(&deg0[ei0[EE + i]], 1);
        atomicAdd(&deg1[ei1[EE + i]], 1);
    }
}

// ---------------- scan: exclusive prefix sum -> rowptr + cursor (2 blocks) ----------------
__global__ __launch_bounds__(1024) void scan2(const int* __restrict__ deg0, int* __restrict__ rp0,
                                              int* __restrict__ pos0,
                                              const int* __restrict__ deg1, int* __restrict__ rp1,
                                              int* __restrict__ pos1) {
    const int* deg = blockIdx.x ? deg1 : deg0;
    int* rp  = blockIdx.x ? rp1  : rp0;
    int* pos = blockIdx.x ? pos1 : pos0;
    __shared__ int wsum[16];
    __shared__ int wpre[16];
    int t = threadIdx.x, lane = t & 63, wv = t >> 6;
    int carry = 0;
    for (int base = 0; base < NN; base += 1024) {
        int idx = base + t;
        int v = (idx < NN) ? deg[idx] : 0;
        int x = v;
#pragma unroll
        for (int off = 1; off < 64; off <<= 1) {
            int y = __shfl_up(x, off, 64);
            if (lane >= off) x += y;
        }
        if (lane == 63) wsum[wv] = x;
        __syncthreads();
        if (t == 0) {
            int s = 0;
            for (int i = 0; i < 16; ++i) { wpre[i] = s; s += wsum[i]; }
            wsum[0] = s;  // chunk total
        }
        __syncthreads();
        int excl = carry + wpre[wv] + x - v;
        if (idx < NN) { rp[idx] = excl; pos[idx] = excl; }
        carry += wsum[0];
        __syncthreads();
    }
    if (t == 0) rp[NN] = carry;
}

// ---------------- scatter edges into CSR order (by dst) ----------------
__global__ void scatter(const int* __restrict__ ei, const float* __restrict__ ew,
                        int* __restrict__ pos, int2* __restrict__ ecsr) {
    long i = (long)blockIdx.x * blockDim.x + threadIdx.x;
    long stride = (long)gridDim.x * blockDim.x;
    for (; i < EE; i += stride) {
        int dst = ei[EE + i];
        int k = atomicAdd(&pos[dst], 1);
        ecsr[k] = make_int2(ei[i], __float_as_int(ew[i]));
    }
}

// ---------------- k1: x1 = X@W1_1 (wave per node) ----------------
__global__ __launch_bounds__(256) void k1(const float* __restrict__ X,
                                          const float* __restrict__ W1,
                                          float* __restrict__ x1) {
    __shared__ float Ws[128 * 16];
    __shared__ float Xs[4][4][132];  // wave, b, c (+4 pad)
    int t = threadIdx.x;
    for (int i = t; i < 2048; i += 256) Ws[i] = W1[i];
    int w = t >> 6, lane = t & 63;
    int n = blockIdx.x * 4 + w;
    for (int bb = 0; bb < 2; ++bb) {
        int b = bb * 2 + (lane >> 5);
        int c4 = (lane & 31) * 4;
        float4 v = *reinterpret_cast<const float4*>(&X[((long)b * NN + n) * 128 + c4]);
        *reinterpret_cast<float4*>(&Xs[w][b][c4]) = v;
    }
    __syncthreads();
    int b = lane >> 4, h = lane & 15;
    float acc = 0.f;
#pragma unroll 8
    for (int c = 0; c < 128; ++c) acc += Xs[w][b][c] * Ws[c * 16 + h];
    x1[(long)n * 64 + lane] = acc;
}

// ---------------- k3: layer1 gather+epilogue + x2 = h1@W1_2 (8 nodes/block) ----------------
__global__ __launch_bounds__(256) void k3(const float* __restrict__ x1,
                                          const int2* __restrict__ ecsr0,
                                          const int* __restrict__ rp0,
                                          const float* __restrict__ W2_1,
                                          const float* __restrict__ U1,
                                          const float* __restrict__ V1,
                                          const float* __restrict__ W1_2,
                                          float* __restrict__ x2) {
    __shared__ float W12s[16 * 64];
    __shared__ float U1s[256];
    __shared__ float V1s[256];
    __shared__ float W21s[16];
    __shared__ float x1s[64];
    __shared__ float h1s[64];
    __shared__ float aggs[4][64];
    int t = threadIdx.x;
    for (int i = t; i < 1024; i += 256) W12s[i] = W1_2[i];
    U1s[t] = U1[t];
    V1s[t] = V1[t];
    if (t < 16) W21s[t] = W2_1[t];
    int w = t >> 6, lane = t & 63;
    for (int ni = 0; ni < 8; ++ni) {
        int n = blockIdx.x * 8 + ni;
        __syncthreads();  // protect x1s/aggs/h1s reuse across iterations
        if (t < 64) x1s[t] = x1[(long)n * 64 + t];
        int start = rp0[n], end = rp0[n + 1];
        // gather: wave w takes edges start+w, start+w+4, ... with 2-deep unroll
        float a0 = 0.f, a1 = 0.f;
        int e = start + w;
        for (; e + 4 < end; e += 8) {
            int2 s0 = ecsr0[e];
            int2 s1 = ecsr0[e + 4];
            a0 += __int_as_float(s0.y) * x1[(long)s0.x * 64 + lane];
            a1 += __int_as_float(s1.y) * x1[(long)s1.x * 64 + lane];
        }
        if (e < end) {
            int2 s0 = ecsr0[e];
            a0 += __int_as_float(s0.y) * x1[(long)s0.x * 64 + lane];
        }
        aggs[w][lane] = a0 + a1;
        __syncthreads();
        if (t < 64) aggs[0][t] = aggs[0][t] + aggs[1][t] + aggs[2][t] + aggs[3][t];
        __syncthreads();
        if (t < 64) {
            int b = t >> 4, h = t & 15;
            float av = 0.f, xu = 0.f;
#pragma unroll
            for (int k = 0; k < 16; ++k) {
                av += aggs[0][b * 16 + k] * V1s[k * 16 + h];
                xu += x1s[b * 16 + k] * U1s[k * 16 + h];
            }
            float c = fmaxf((float)(end - start), 1.f);
            float a = xu + W21s[h] * av / c;
            float s = a, s2 = a * a;
#pragma unroll
            for (int off = 32; off >= 1; off >>= 1) {
                s += __shfl_xor(s, off, 64);
                s2 += __shfl_xor(s2, off, 64);
            }
            float mean = s * (1.f / 64.f);
            float var = s2 * (1.f / 64.f) - mean * mean;
            float norm = (a - mean) * rsqrtf(var + EPS);
            h1s[t] = x1s[t] + fmaxf(norm, 0.f);
        }
        __syncthreads();
        int b2 = t >> 6, j = t & 63;
        float xv = 0.f;
#pragma unroll
        for (int h2 = 0; h2 < 16; ++h2) xv += h1s[b2 * 16 + h2] * W12s[h2 * 64 + j];
        x2[(long)n * 256 + t] = xv;
    }
}

// ---------------- k5: layer2 gather+epilogue -> out (8 nodes/block) ----------------
__global__ __launch_bounds__(256) void k5(const float* __restrict__ x2,
                                          const int2* __restrict__ ecsr1,
                                          const int* __restrict__ rp1,
                                          const float* __restrict__ W2_2,
                                          const float* __restrict__ U2,
                                          const float* __restrict__ V2,
                                          float* __restrict__ out) {
    __shared__ float U2s[4096];
    __shared__ float V2s[4096];
    __shared__ float x2s[256];
    __shared__ float aggp[256];
    __shared__ float red[16];
    __shared__ float W22s[64];
    int t = threadIdx.x;
    for (int i = t; i < 4096; i += 256) { U2s[i] = U2[i]; V2s[i] = V2[i]; }
    if (t < 64) W22s[t] = W2_2[t];
    for (int ni = 0; ni < 8; ++ni) {
        int n = blockIdx.x * 8 + ni;
        __syncthreads();  // protect x2s/aggp reuse
        float xv = x2[(long)n * 256 + t];
        x2s[t] = xv;
        int start = rp1[n], end = rp1[n + 1];
        float a0 = 0.f, a1 = 0.f, a2 = 0.f, a3 = 0.f;
        int e = start;
        for (; e + 3 < end; e += 4) {
            int2 s0 = ecsr1[e];
            int2 s1 = ecsr1[e + 1];
            int2 s2 = ecsr1[e + 2];
            int2 s3 = ecsr1[e + 3];
            a0 += __int_as_float(s0.y) * x2[(long)s0.x * 256 + t];
            a1 += __int_as_float(s1.y) * x2[(long)s1.x * 256 + t];
            a2 += __int_as_float(s2.y) * x2[(long)s2.x * 256 + t];
            a3 += __int_as_float(s3.y) * x2[(long)s3.x * 256 + t];
        }
        for (; e < end; ++e) {
            int2 s0 = ecsr1[e];
            a0 += __int_as_float(s0.y) * x2[(long)s0.x * 256 + t];
        }
        aggp[t] = (a0 + a1) + (a2 + a3);
        __syncthreads();
        int b = t >> 6, j = t & 63;
        float av = 0.f, xu = 0.f;
#pragma unroll 8
        for (int k = 0; k < 64; ++k) {
            av += aggp[b * 64 + k] * V2s[k * 64 + j];
            xu += x2s[b * 64 + k] * U2s[k * 64 + j];
        }
        float c = fmaxf((float)(end - start), 1.f);
        float a = xu + W22s[j] * av / c;
        float s = a, s2 = a * a;
#pragma unroll
        for (int off = 32; off >= 1; off >>= 1) {
            s += __shfl_xor(s, off, 64);
            s2 += __shfl_xor(s2, off, 64);
        }
        int wv = t >> 6, lane = t & 63;
        if (lane == 0) { red[wv] = s; red[8 + wv] = s2; }
        __syncthreads();
        float S = red[0] + red[1] + red[2] + red[3];
        float S2 = red[8] + red[9] + red[10] + red[11];
        float mean = S * (1.f / 256.f);
        float var = S2 * (1.f / 256.f) - mean * mean;
        float norm = (a - mean) * rsqrtf(var + EPS);
        out[((long)b * NN + n) * 64 + j] = xv + fmaxf(norm, 0.f);
    }
}

extern "C" void kernel_launch(void* const* d_in, const int* in_sizes, int n_in,
                              void* d_out, int out_size, void* d_ws, size_t ws_size,
                              hipStream_t stream) {
    const float* X    = (const float*)d_in[0];
    const int*   ei0  = (const int*)d_in[1];
    const float* ew0  = (const float*)d_in[2];
    const int*   ei1  = (const int*)d_in[3];
    const float* ew1  = (const float*)d_in[4];
    const float* W1_1 = (const float*)d_in[8];
    const float* W2_1 = (const float*)d_in[9];
    const float* U1   = (const float*)d_in[10];
    const float* V1   = (const float*)d_in[11];
    const float* W1_2 = (const float*)d_in[12];
    const float* W2_2 = (const float*)d_in[13];
    const float* U2   = (const float*)d_in[14];
    const float* V2   = (const float*)d_in[15];
    float* out = (float*)d_out;
    char* ws = (char*)d_ws;

    const long MB = 1000000L;
    float* x1   = (float*)(ws + 0L);          // 25.6 MB
    float* x2   = (float*)(ws + 32 * MB);     // 102.4 MB (ends 134.4 MB)
    int*   deg0 = (int*)(ws + 140 * MB);      // 400 KB
    int*   rp0  = (int*)(ws + 141 * MB);      // 400 KB + 4
    int*   pos0 = (int*)(ws + 142 * MB);      // 400 KB
    int*   deg1 = (int*)(ws + 143 * MB);
    int*   rp1  = (int*)(ws + 144 * MB);
    int*   pos1 = (int*)(ws + 145 * MB);
    int2*  ecsr0 = (int2*)(ws + 146 * MB);    // 12.8 MB
    int2*  ecsr1 = (int2*)(ws + 160 * MB);    // 12.8 MB (ends 172.8 MB)

    // zero deg/rp/pos region (6 MB)
    fill0<<<1536, 256, 0, stream>>>((float4*)(ws + 140 * MB), 6 * MB / 16);
    hist<<<2048, 256, 0, stream>>>(ei0, ei1, deg0, deg1);
    scan2<<<2, 1024, 0, stream>>>(deg0, rp0, pos0, deg1, rp1, pos1);
    scatter<<<2048, 256, 0, stream>>>(ei0, ew0, pos0, ecsr0);
    scatter<<<2048, 256, 0, stream>>>(ei1, ew1, pos1, ecsr1);
    k1<<<25000, 256, 0, stream>>>(X, W1_1, x1);
    k3<<<12500, 256, 0, stream>>>(x1, ecsr0, rp0, W2_1, U1, V1, W1_2, x2);
    k5<<<12500, 256, 0, stream>>>(x2, ecsr1, rp1, W2_2, U2, V2, out);
}

// Round 3
// 959.392 us; speedup vs baseline: 2.5778x; 1.3317x over previous
//
#include <hip/hip_runtime.h>

#define NN 100000
#define EE 1600000
#define EPS 1e-5f

// ---------------- fill zero (float4 grid-stride) ----------------
__global__ void fill0(float4* __restrict__ p, long n4) {
    long i = (long)blockIdx.x * blockDim.x + threadIdx.x;
    long stride = (long)gridDim.x * blockDim.x;
    float4 z = make_float4(0.f, 0.f, 0.f, 0.f);
    for (; i < n4; i += stride) p[i] = z;
}

// ---------------- hist: degree count for both edge lists ----------------
__global__ void hist(const int* __restrict__ ei0, const int* __restrict__ ei1,
                     int* __restrict__ deg0, int* __restrict__ deg1) {
    long i = (long)blockIdx.x * blockDim.x + threadIdx.x;
    long stride = (long)gridDim.x * blockDim.x;
    for (; i < EE; i += stride) {
        atomicAdd(&deg0[ei0[EE + i]], 1);
        atomicAdd(&deg1[ei1[EE + i]], 1);
    }
}

// ---------------- scan: exclusive prefix sum -> rowptr + cursor (2 blocks) ----------------
__global__ __launch_bounds__(1024) void scan2(const int* __restrict__ deg0, int* __restrict__ rp0,
                                              int* __restrict__ pos0,
                                              const int* __restrict__ deg1, int* __restrict__ rp1,
                                              int* __restrict__ pos1) {
    const int* deg = blockIdx.x ? deg1 : deg0;
    int* rp  = blockIdx.x ? rp1  : rp0;
    int* pos = blockIdx.x ? pos1 : pos0;
    __shared__ int wsum[16];
    __shared__ int wpre[16];
    int t = threadIdx.x, lane = t & 63, wv = t >> 6;
    int carry = 0;
    for (int base = 0; base < NN; base += 1024) {
        int idx = base + t;
        int v = (idx < NN) ? deg[idx] : 0;
        int x = v;
#pragma unroll
        for (int off = 1; off < 64; off <<= 1) {
            int y = __shfl_up(x, off, 64);
            if (lane >= off) x += y;
        }
        if (lane == 63) wsum[wv] = x;
        __syncthreads();
        if (t == 0) {
            int s = 0;
            for (int i = 0; i < 16; ++i) { wpre[i] = s; s += wsum[i]; }
            wsum[0] = s;  // chunk total
        }
        __syncthreads();
        int excl = carry + wpre[wv] + x - v;
        if (idx < NN) { rp[idx] = excl; pos[idx] = excl; }
        carry += wsum[0];
        __syncthreads();
    }
    if (t == 0) rp[NN] = carry;
}

// ---------------- scatter edges into CSR order (by dst) ----------------
__global__ void scatter(const int* __restrict__ ei, const float* __restrict__ ew,
                        int* __restrict__ pos, int2* __restrict__ ecsr) {
    long i = (long)blockIdx.x * blockDim.x + threadIdx.x;
    long stride = (long)gridDim.x * blockDim.x;
    for (; i < EE; i += stride) {
        int dst = ei[EE + i];
        int k = atomicAdd(&pos[dst], 1);
        ecsr[k] = make_int2(ei[i], __float_as_int(ew[i]));
    }
}

// ---------------- prew: WU = W1_2@U2, WV = W1_2@V2 (16x64 each) ----------------
__global__ __launch_bounds__(256) void prew(const float* __restrict__ W1_2,
                                            const float* __restrict__ U2,
                                            const float* __restrict__ V2,
                                            float* __restrict__ WU,
                                            float* __restrict__ WV) {
    int t = threadIdx.x;
    for (int i = t; i < 1024; i += 256) {
        int k = i >> 6, j = i & 63;
        float su = 0.f, sv = 0.f;
        for (int m = 0; m < 64; ++m) {
            float wm = W1_2[k * 64 + m];
            su += wm * U2[m * 64 + j];
            sv += wm * V2[m * 64 + j];
        }
        WU[i] = su;
        WV[i] = sv;
    }
}

// ---------------- k1: x1 = X@W1_1 (wave per node) ----------------
__global__ __launch_bounds__(256) void k1(const float* __restrict__ X,
                                          const float* __restrict__ W1,
                                          float* __restrict__ x1) {
    __shared__ float Ws[128 * 16];
    __shared__ float Xs[4][4][132];  // wave, b, c (+4 pad)
    int t = threadIdx.x;
    for (int i = t; i < 2048; i += 256) Ws[i] = W1[i];
    int w = t >> 6, lane = t & 63;
    int n = blockIdx.x * 4 + w;
    for (int bb = 0; bb < 2; ++bb) {
        int b = bb * 2 + (lane >> 5);
        int c4 = (lane & 31) * 4;
        float4 v = *reinterpret_cast<const float4*>(&X[((long)b * NN + n) * 128 + c4]);
        *reinterpret_cast<float4*>(&Xs[w][b][c4]) = v;
    }
    __syncthreads();
    int b = lane >> 4, h = lane & 15;
    float acc = 0.f;
#pragma unroll 8
    for (int c = 0; c < 128; ++c) acc += Xs[w][b][c] * Ws[c * 16 + h];
    x1[(long)n * 64 + lane] = acc;
}

// ---------------- k3: layer1 gather+epilogue -> h1 (wave per node) ----------------
__global__ __launch_bounds__(256) void k3(const float* __restrict__ x1,
                                          const int2* __restrict__ ecsr0,
                                          const int* __restrict__ rp0,
                                          const float* __restrict__ W2_1,
                                          const float* __restrict__ U1,
                                          const float* __restrict__ V1,
                                          float* __restrict__ h1out) {
    __shared__ float U1s[256];
    __shared__ float V1s[256];
    __shared__ float W21s[16];
    __shared__ float x1s[4][64];
    __shared__ float aggs[4][64];
    int t = threadIdx.x;
    U1s[t] = U1[t];
    V1s[t] = V1[t];
    if (t < 16) W21s[t] = W2_1[t];
    int w = t >> 6, lane = t & 63;
    int n = blockIdx.x * 4 + w;
    __syncthreads();
    float xr = x1[(long)n * 64 + lane];
    int start = rp0[n], end = rp0[n + 1];
    float a0 = 0.f, a1 = 0.f;
    int e = start;
    for (; e + 1 < end; e += 2) {
        int2 r0 = ecsr0[e];
        int2 r1 = ecsr0[e + 1];
        a0 += __int_as_float(r0.y) * x1[(long)r0.x * 64 + lane];
        a1 += __int_as_float(r1.y) * x1[(long)r1.x * 64 + lane];
    }
    if (e < end) {
        int2 r0 = ecsr0[e];
        a0 += __int_as_float(r0.y) * x1[(long)r0.x * 64 + lane];
    }
    // wave-local LDS stash (no cross-wave sharing -> no barrier needed)
    x1s[w][lane] = xr;
    aggs[w][lane] = a0 + a1;
    int b = lane >> 4, h = lane & 15;
    float av = 0.f, xu = 0.f;
#pragma unroll
    for (int k = 0; k < 16; ++k) {
        av += aggs[w][b * 16 + k] * V1s[k * 16 + h];
        xu += x1s[w][b * 16 + k] * U1s[k * 16 + h];
    }
    float c = fmaxf((float)(end - start), 1.f);
    float a = xu + W21s[h] * av / c;
    float s = a, s2 = a * a;
#pragma unroll
    for (int off = 32; off >= 1; off >>= 1) {
        s += __shfl_xor(s, off, 64);
        s2 += __shfl_xor(s2, off, 64);
    }
    float mean = s * (1.f / 64.f);
    float var = s2 * (1.f / 64.f) - mean * mean;
    float norm = (a - mean) * rsqrtf(var + EPS);
    h1out[(long)n * 64 + lane] = xr + fmaxf(norm, 0.f);
}

// ---------------- k5: layer2 gather(h1)+epilogue -> out (wave per node) ----------------
__global__ __launch_bounds__(256) void k5(const float* __restrict__ h1,
                                          const int2* __restrict__ ecsr1,
                                          const int* __restrict__ rp1,
                                          const float* __restrict__ W2_2,
                                          const float* __restrict__ W1_2,
                                          const float* __restrict__ WU,
                                          const float* __restrict__ WV,
                                          float* __restrict__ out) {
    __shared__ float W12s[1024];
    __shared__ float WUs[1024];
    __shared__ float WVs[1024];
    __shared__ float W22s[64];
    __shared__ float h1s[4][64];
    __shared__ float aggs[4][64];
    int t = threadIdx.x;
    for (int i = t; i < 1024; i += 256) {
        W12s[i] = W1_2[i];
        WUs[i] = WU[i];
        WVs[i] = WV[i];
    }
    if (t < 64) W22s[t] = W2_2[t];
    int w = t >> 6, lane = t & 63;
    int n = blockIdx.x * 4 + w;
    __syncthreads();
    float hv = h1[(long)n * 64 + lane];
    int start = rp1[n], end = rp1[n + 1];
    float a0 = 0.f, a1 = 0.f;
    int e = start;
    for (; e + 1 < end; e += 2) {
        int2 r0 = ecsr1[e];
        int2 r1 = ecsr1[e + 1];
        a0 += __int_as_float(r0.y) * h1[(long)r0.x * 64 + lane];
        a1 += __int_as_float(r1.y) * h1[(long)r1.x * 64 + lane];
    }
    if (e < end) {
        int2 r0 = ecsr1[e];
        a0 += __int_as_float(r0.y) * h1[(long)r0.x * 64 + lane];
    }
    h1s[w][lane] = hv;
    aggs[w][lane] = a0 + a1;
    float c = fmaxf((float)(end - start), 1.f);
    float x2b[4], ab[4];
    float s = 0.f, s2 = 0.f;
#pragma unroll
    for (int b = 0; b < 4; ++b) {
        float x2 = 0.f, xu = 0.f, av = 0.f;
#pragma unroll
        for (int k = 0; k < 16; ++k) {
            float hk = h1s[w][b * 16 + k];
            float gk = aggs[w][b * 16 + k];
            x2 += hk * W12s[k * 64 + lane];
            xu += hk * WUs[k * 64 + lane];
            av += gk * WVs[k * 64 + lane];
        }
        float a = xu + W22s[lane] * av / c;
        x2b[b] = x2;
        ab[b] = a;
        s += a;
        s2 += a * a;
    }
#pragma unroll
    for (int off = 32; off >= 1; off >>= 1) {
        s += __shfl_xor(s, off, 64);
        s2 += __shfl_xor(s2, off, 64);
    }
    float mean = s * (1.f / 256.f);
    float var = s2 * (1.f / 256.f) - mean * mean;
    float rs = rsqrtf(var + EPS);
#pragma unroll
    for (int b = 0; b < 4; ++b) {
        float norm = (ab[b] - mean) * rs;
        out[((long)b * NN + n) * 64 + lane] = x2b[b] + fmaxf(norm, 0.f);
    }
}

extern "C" void kernel_launch(void* const* d_in, const int* in_sizes, int n_in,
                              void* d_out, int out_size, void* d_ws, size_t ws_size,
                              hipStream_t stream) {
    const float* X    = (const float*)d_in[0];
    const int*   ei0  = (const int*)d_in[1];
    const float* ew0  = (const float*)d_in[2];
    const int*   ei1  = (const int*)d_in[3];
    const float* ew1  = (const float*)d_in[4];
    const float* W1_1 = (const float*)d_in[8];
    const float* W2_1 = (const float*)d_in[9];
    const float* U1   = (const float*)d_in[10];
    const float* V1   = (const float*)d_in[11];
    const float* W1_2 = (const float*)d_in[12];
    const float* W2_2 = (const float*)d_in[13];
    const float* U2   = (const float*)d_in[14];
    const float* V2   = (const float*)d_in[15];
    float* out = (float*)d_out;
    char* ws = (char*)d_ws;

    const long MB = 1000000L;
    float* x1   = (float*)(ws + 0L);           // 25.6 MB
    float* h1   = (float*)(ws + 26 * MB);      // 25.6 MB
    int*   deg0 = (int*)(ws + 52 * MB);        // 400 KB
    int*   deg1 = (int*)(ws + 52 * MB + 400000L); // 400 KB (contiguous with deg0)
    int*   rp0  = (int*)(ws + 53 * MB);        // 400 KB + 4
    int*   pos0 = (int*)(ws + 54 * MB);
    int*   rp1  = (int*)(ws + 55 * MB);
    int*   pos1 = (int*)(ws + 56 * MB);
    int2*  ecsr0 = (int2*)(ws + 57 * MB);      // 12.8 MB
    int2*  ecsr1 = (int2*)(ws + 70 * MB);      // 12.8 MB
    float* WU   = (float*)(ws + 83 * MB);      // 4 KB
    float* WV   = (float*)(ws + 83 * MB + 4096); // 4 KB

    // zero deg0+deg1 (contiguous 800 KB)
    fill0<<<196, 256, 0, stream>>>((float4*)deg0, 800000L / 16);
    hist<<<2048, 256, 0, stream>>>(ei0, ei1, deg0, deg1);
    scan2<<<2, 1024, 0, stream>>>(deg0, rp0, pos0, deg1, rp1, pos1);
    scatter<<<2048, 256, 0, stream>>>(ei0, ew0, pos0, ecsr0);
    scatter<<<2048, 256, 0, stream>>>(ei1, ew1, pos1, ecsr1);
    prew<<<1, 256, 0, stream>>>(W1_2, U2, V2, WU, WV);
    k1<<<25000, 256, 0, stream>>>(X, W1_1, x1);
    k3<<<25000, 256, 0, stream>>>(x1, ecsr0, rp0, W2_1, U1, V1, h1);
    k5<<<25000, 256, 0, stream>>>(h1, ecsr1, rp1, W2_2, W1_2, WU, WV, out);
}

// Round 5
// 944.492 us; speedup vs baseline: 2.6185x; 1.0158x over previous
//
#include <hip/hip_runtime.h>

#define NN 100000
#define EE 1600000
#define EPS 1e-5f

__device__ __forceinline__ ushort f2bf(float f) {
    uint u = __float_as_uint(f);
    uint r = (u + 0x7FFF + ((u >> 16) & 1)) >> 16;  // RNE
    return (ushort)r;
}
__device__ __forceinline__ float bf2f(ushort u) {
    return __uint_as_float(((uint)u) << 16);
}

// ---------------- fill zero (float4 grid-stride) ----------------
__global__ void fill0(float4* __restrict__ p, long n4) {
    long i = (long)blockIdx.x * blockDim.x + threadIdx.x;
    long stride = (long)gridDim.x * blockDim.x;
    float4 z = make_float4(0.f, 0.f, 0.f, 0.f);
    for (; i < n4; i += stride) p[i] = z;
}

// ---------------- hist: degree count + write CSR pad sentinels ----------------
__global__ void hist(const int* __restrict__ ei0, const int* __restrict__ ei1,
                     int* __restrict__ deg0, int* __restrict__ deg1,
                     int2* __restrict__ ecsr0, int2* __restrict__ ecsr1) {
    if (blockIdx.x == 0 && threadIdx.x < 16) {
        int i = threadIdx.x;
        if (i < 8) ecsr0[EE + i] = make_int2(0, 0);
        else       ecsr1[EE + i - 8] = make_int2(0, 0);
    }
    long i = (long)blockIdx.x * blockDim.x + threadIdx.x;
    long stride = (long)gridDim.x * blockDim.x;
    for (; i < EE; i += stride) {
        atomicAdd(&deg0[ei0[EE + i]], 1);
        atomicAdd(&deg1[ei1[EE + i]], 1);
    }
}

// ---------------- scan2: thread-owns-range exclusive scan (1 block per CSR) ----------------
__global__ __launch_bounds__(1024) void scan2(const int* __restrict__ deg0, int* __restrict__ rp0,
                                              int* __restrict__ pos0,
                                              const int* __restrict__ deg1, int* __restrict__ rp1,
                                              int* __restrict__ pos1) {
    const int* deg = blockIdx.x ? deg1 : deg0;
    int* rp  = blockIdx.x ? rp1  : rp0;
    int* pos = blockIdx.x ? pos1 : pos0;
    const int C = 98;  // 1024*98 >= 100000
    int t = threadIdx.x;
    int beg = t * C, fin = beg + C < NN ? beg + C : NN;
    if (beg > NN) beg = NN;
    int local = 0;
    for (int i = beg; i < fin; ++i) local += deg[i];
    int lane = t & 63, wv = t >> 6;
    int x = local;
#pragma unroll
    for (int off = 1; off < 64; off <<= 1) {
        int y = __shfl_up(x, off, 64);
        if (lane >= off) x += y;
    }
    __shared__ int wsum[16];
    __shared__ int wpre[17];
    if (lane == 63) wsum[wv] = x;
    __syncthreads();
    if (t == 0) {
        int s = 0;
        for (int i = 0; i < 16; ++i) { wpre[i] = s; s += wsum[i]; }
        wpre[16] = s;
    }
    __syncthreads();
    int running = wpre[wv] + x - local;  // exclusive prefix for this thread's range
    for (int i = beg; i < fin; ++i) {
        rp[i] = running;
        pos[i] = running;
        running += deg[i];
    }
    if (t == 0) rp[NN] = wpre[16];
}

// ---------------- scatter edges into CSR order (by dst) ----------------
__global__ void scatter(const int* __restrict__ ei, const float* __restrict__ ew,
                        int* __restrict__ pos, int2* __restrict__ ecsr) {
    long i = (long)blockIdx.x * blockDim.x + threadIdx.x;
    long stride = (long)gridDim.x * blockDim.x;
    for (; i < EE; i += stride) {
        int dst = ei[EE + i];
        int k = atomicAdd(&pos[dst], 1);
        ecsr[k] = make_int2(ei[i], __float_as_int(ew[i]));
    }
}

// ---------------- prew: WU = W1_2@U2, WV = W1_2@V2 (16x64 each) ----------------
__global__ __launch_bounds__(256) void prew(const float* __restrict__ W1_2,
                                            const float* __restrict__ U2,
                                            const float* __restrict__ V2,
                                            float* __restrict__ WU,
                                            float* __restrict__ WV) {
    int t = threadIdx.x;
    for (int i = t; i < 1024; i += 256) {
        int k = i >> 6, j = i & 63;
        float su = 0.f, sv = 0.f;
        for (int m = 0; m < 64; ++m) {
            float wm = W1_2[k * 64 + m];
            su += wm * U2[m * 64 + j];
            sv += wm * V2[m * 64 + j];
        }
        WU[i] = su;
        WV[i] = sv;
    }
}

// ---------------- k1: x1 = X@W1_1 (wave per node), fp32 + bf16 copies ----------------
__global__ __launch_bounds__(256) void k1(const float* __restrict__ X,
                                          const float* __restrict__ W1,
                                          float* __restrict__ x1,
                                          ushort* __restrict__ x1g) {
    __shared__ float Ws[128 * 16];
    __shared__ float Xs[4][4][132];  // wave, b, c (+4 pad)
    int t = threadIdx.x;
    for (int i = t; i < 2048; i += 256) Ws[i] = W1[i];
    int w = t >> 6, lane = t & 63;
    int n = blockIdx.x * 4 + w;
    for (int bb = 0; bb < 2; ++bb) {
        int b = bb * 2 + (lane >> 5);
        int c4 = (lane & 31) * 4;
        float4 v = *reinterpret_cast<const float4*>(&X[((long)b * NN + n) * 128 + c4]);
        *reinterpret_cast<float4*>(&Xs[w][b][c4]) = v;
    }
    __syncthreads();
    int b = lane >> 4, h = lane & 15;
    float acc = 0.f;
#pragma unroll 8
    for (int c = 0; c < 128; ++c) acc += Xs[w][b][c] * Ws[c * 16 + h];
    x1[(long)n * 64 + lane] = acc;
    x1g[(long)n * 64 + lane] = f2bf(acc);
}

// ---------------- k3: layer1 gather+epilogue -> h1 fp32 + h1g bf16 ----------------
__global__ __launch_bounds__(256) void k3(const float* __restrict__ x1,
                                          const ushort* __restrict__ x1g,
                                          const int2* __restrict__ ecsr0,
                                          const int* __restrict__ rp0,
                                          const float* __restrict__ W2_1,
                                          const float* __restrict__ U1,
                                          const float* __restrict__ V1,
                                          float* __restrict__ h1out,
                                          ushort* __restrict__ h1g) {
    __shared__ float U1s[256];
    __shared__ float V1s[256];
    __shared__ float W21s[16];
    __shared__ float x1s[4][64];
    __shared__ float aggs[4][64];
    int t = threadIdx.x;
    U1s[t] = U1[t];
    V1s[t] = V1[t];
    if (t < 16) W21s[t] = W2_1[t];
    int w = t >> 6, lane = t & 63;
    int n = blockIdx.x * 4 + w;
    __syncthreads();
    float xr = x1[(long)n * 64 + lane];
    int start = rp0[n], end = rp0[n + 1];
    float acc = 0.f;
    for (int e = start; e < end; e += 8) {
        int2 r[8];
#pragma unroll
        for (int i = 0; i < 8; ++i) r[i] = ecsr0[e + i];  // memory-safe (global pad)
        float v[8];
#pragma unroll
        for (int i = 0; i < 8; ++i) v[i] = bf2f(x1g[(long)r[i].x * 64 + lane]);
#pragma unroll
        for (int i = 0; i < 8; ++i) {
            float wm = (e + i < end) ? __int_as_float(r[i].y) : 0.f;  // mask tail
            acc += wm * v[i];
        }
    }
    x1s[w][lane] = xr;
    aggs[w][lane] = acc;
    int b = lane >> 4, h = lane & 15;
    float av = 0.f, xu = 0.f;
#pragma unroll
    for (int k = 0; k < 16; ++k) {
        av += aggs[w][b * 16 + k] * V1s[k * 16 + h];
        xu += x1s[w][b * 16 + k] * U1s[k * 16 + h];
    }
    float c = fmaxf((float)(end - start), 1.f);
    float a = xu + W21s[h] * av / c;
    float s = a, s2 = a * a;
#pragma unroll
    for (int off = 32; off >= 1; off >>= 1) {
        s += __shfl_xor(s, off, 64);
        s2 += __shfl_xor(s2, off, 64);
    }
    float mean = s * (1.f / 64.f);
    float var = s2 * (1.f / 64.f) - mean * mean;
    float norm = (a - mean) * rsqrtf(var + EPS);
    float hv = xr + fmaxf(norm, 0.f);
    h1out[(long)n * 64 + lane] = hv;
    h1g[(long)n * 64 + lane] = f2bf(hv);
}

// ---------------- k5: layer2 gather(h1g)+epilogue -> out ----------------
__global__ __launch_bounds__(256) void k5(const float* __restrict__ h1,
                                          const ushort* __restrict__ h1g,
                                          const int2* __restrict__ ecsr1,
                                          const int* __restrict__ rp1,
                                          const float* __restrict__ W2_2,
                                          const float* __restrict__ W1_2,
                                          const float* __restrict__ WU,
                                          const float* __restrict__ WV,
                                          float* __restrict__ out) {
    __shared__ float W12s[1024];
    __shared__ float WUs[1024];
    __shared__ float WVs[1024];
    __shared__ float W22s[64];
    __shared__ float h1s[4][64];
    __shared__ float aggs[4][64];
    int t = threadIdx.x;
    for (int i = t; i < 1024; i += 256) {
        W12s[i] = W1_2[i];
        WUs[i] = WU[i];
        WVs[i] = WV[i];
    }
    if (t < 64) W22s[t] = W2_2[t];
    int w = t >> 6, lane = t & 63;
    int n = blockIdx.x * 4 + w;
    __syncthreads();
    float hv = h1[(long)n * 64 + lane];
    int start = rp1[n], end = rp1[n + 1];
    float acc = 0.f;
    for (int e = start; e < end; e += 8) {
        int2 r[8];
#pragma unroll
        for (int i = 0; i < 8; ++i) r[i] = ecsr1[e + i];  // memory-safe (global pad)
        float v[8];
#pragma unroll
        for (int i = 0; i < 8; ++i) v[i] = bf2f(h1g[(long)r[i].x * 64 + lane]);
#pragma unroll
        for (int i = 0; i < 8; ++i) {
            float wm = (e + i < end) ? __int_as_float(r[i].y) : 0.f;  // mask tail
            acc += wm * v[i];
        }
    }
    h1s[w][lane] = hv;
    aggs[w][lane] = acc;
    float c = fmaxf((float)(end - start), 1.f);
    float x2b[4], ab[4];
    float s = 0.f, s2 = 0.f;
#pragma unroll
    for (int b = 0; b < 4; ++b) {
        float x2 = 0.f, xu = 0.f, av = 0.f;
#pragma unroll
        for (int k = 0; k < 16; ++k) {
            float hk = h1s[w][b * 16 + k];
            float gk = aggs[w][b * 16 + k];
            x2 += hk * W12s[k * 64 + lane];
            xu += hk * WUs[k * 64 + lane];
            av += gk * WVs[k * 64 + lane];
        }
        float a = xu + W22s[lane] * av / c;
        x2b[b] = x2;
        ab[b] = a;
        s += a;
        s2 += a * a;
    }
#pragma unroll
    for (int off = 32; off >= 1; off >>= 1) {
        s += __shfl_xor(s, off, 64);
        s2 += __shfl_xor(s2, off, 64);
    }
    float mean = s * (1.f / 256.f);
    float var = s2 * (1.f / 256.f) - mean * mean;
    float rs = rsqrtf(var + EPS);
#pragma unroll
    for (int b = 0; b < 4; ++b) {
        float norm = (ab[b] - mean) * rs;
        out[((long)b * NN + n) * 64 + lane] = x2b[b] + fmaxf(norm, 0.f);
    }
}

extern "C" void kernel_launch(void* const* d_in, const int* in_sizes, int n_in,
                              void* d_out, int out_size, void* d_ws, size_t ws_size,
                              hipStream_t stream) {
    const float* X    = (const float*)d_in[0];
    const int*   ei0  = (const int*)d_in[1];
    const float* ew0  = (const float*)d_in[2];
    const int*   ei1  = (const int*)d_in[3];
    const float* ew1  = (const float*)d_in[4];
    const float* W1_1 = (const float*)d_in[8];
    const float* W2_1 = (const float*)d_in[9];
    const float* U1   = (const float*)d_in[10];
    const float* V1   = (const float*)d_in[11];
    const float* W1_2 = (const float*)d_in[12];
    const float* W2_2 = (const float*)d_in[13];
    const float* U2   = (const float*)d_in[14];
    const float* V2   = (const float*)d_in[15];
    float* out = (float*)d_out;
    char* ws = (char*)d_ws;

    const long MB = 1000000L;
    float*  x1   = (float*)(ws + 0L);             // 25.6 MB
    float*  h1   = (float*)(ws + 26 * MB);        // 25.6 MB
    int*    deg0 = (int*)(ws + 52 * MB);          // 400 KB
    int*    deg1 = (int*)(ws + 52 * MB + 400000L);
    int*    rp0  = (int*)(ws + 53 * MB);
    int*    pos0 = (int*)(ws + 54 * MB);
    int*    rp1  = (int*)(ws + 55 * MB);
    int*    pos1 = (int*)(ws + 56 * MB);
    int2*   ecsr0 = (int2*)(ws + 57 * MB);        // 12.8 MB + 64 B pad
    int2*   ecsr1 = (int2*)(ws + 70 * MB);        // 12.8 MB + 64 B pad
    float*  WU   = (float*)(ws + 83 * MB);        // 4 KB
    float*  WV   = (float*)(ws + 83 * MB + 4096);
    ushort* x1g  = (ushort*)(ws + 84 * MB);       // 12.8 MB
    ushort* h1g  = (ushort*)(ws + 97 * MB);       // 12.8 MB (ends 109.8 MB)

    fill0<<<196, 256, 0, stream>>>((float4*)deg0, 800000L / 16);
    hist<<<2048, 256, 0, stream>>>(ei0, ei1, deg0, deg1, ecsr0, ecsr1);
    scan2<<<2, 1024, 0, stream>>>(deg0, rp0, pos0, deg1, rp1, pos1);
    scatter<<<2048, 256, 0, stream>>>(ei0, ew0, pos0, ecsr0);
    scatter<<<2048, 256, 0, stream>>>(ei1, ew1, pos1, ecsr1);
    prew<<<1, 256, 0, stream>>>(W1_2, U2, V2, WU, WV);
    k1<<<25000, 256, 0, stream>>>(X, W1_1, x1, x1g);
    k3<<<25000, 256, 0, stream>>>(x1, x1g, ecsr0, rp0, W2_1, U1, V1, h1, h1g);
    k5<<<25000, 256, 0, stream>>>(h1, h1g, ecsr1, rp1, W2_2, W1_2, WU, WV, out);
}

// Round 6
// 675.102 us; speedup vs baseline: 3.6633x; 1.3990x over previous
//
#include <hip/hip_runtime.h>

#define NN 100000
#define EE 1600000
#define EPS 1e-5f
#define NBLK 196  // ceil(NN/512)

__device__ __forceinline__ ushort f2bf(float f) {
    uint u = __float_as_uint(f);
    uint r = (u + 0x7FFF + ((u >> 16) & 1)) >> 16;  // RNE
    return (ushort)r;
}
__device__ __forceinline__ float bf2f(ushort u) {
    return __uint_as_float(((uint)u) << 16);
}

// ---------------- fill zero (float4 grid-stride) ----------------
__global__ void fill0(float4* __restrict__ p, long n4) {
    long i = (long)blockIdx.x * blockDim.x + threadIdx.x;
    long stride = (long)gridDim.x * blockDim.x;
    float4 z = make_float4(0.f, 0.f, 0.f, 0.f);
    for (; i < n4; i += stride) p[i] = z;
}

// ---------------- hist: degree count + write CSR pad sentinels ----------------
__global__ void hist(const int* __restrict__ ei0, const int* __restrict__ ei1,
                     int* __restrict__ deg0, int* __restrict__ deg1,
                     int2* __restrict__ ecsr0, int2* __restrict__ ecsr1) {
    if (blockIdx.x == 0 && threadIdx.x < 32) {
        int i = threadIdx.x;
        if (i < 16) ecsr0[EE + i] = make_int2(0, 0);
        else        ecsr1[EE + i - 16] = make_int2(0, 0);
    }
    long i = (long)blockIdx.x * blockDim.x + threadIdx.x;
    long stride = (long)gridDim.x * blockDim.x;
    for (; i < EE; i += stride) {
        atomicAdd(&deg0[ei0[EE + i]], 1);
        atomicAdd(&deg1[ei1[EE + i]], 1);
    }
}

// ---------------- scanA: per-block (512 deg) sums ----------------
__global__ __launch_bounds__(256) void scanA(const int* __restrict__ deg0,
                                             const int* __restrict__ deg1,
                                             int* __restrict__ bsum) {
    int which = blockIdx.x >= NBLK;
    const int* deg = which ? deg1 : deg0;
    int blk = blockIdx.x - which * NBLK;
    int base = blk * 512 + threadIdx.x * 2;
    int d0 = base < NN ? deg[base] : 0;
    int d1 = base + 1 < NN ? deg[base + 1] : 0;
    int s = d0 + d1;
#pragma unroll
    for (int off = 1; off < 64; off <<= 1) s += __shfl_xor(s, off, 64);
    __shared__ int ws4[4];
    int lane = threadIdx.x & 63, wv = threadIdx.x >> 6;
    if (lane == 0) ws4[wv] = s;
    __syncthreads();
    if (threadIdx.x == 0) bsum[blockIdx.x] = ws4[0] + ws4[1] + ws4[2] + ws4[3];
}

// ---------------- scanB: exclusive scan of block sums (2 segments) ----------------
__global__ __launch_bounds__(256) void scanB(int* __restrict__ bsum) {
    int seg = blockIdx.x;
    int t = threadIdx.x;
    int v = t < NBLK ? bsum[seg * NBLK + t] : 0;
    int x = v;
    int lane = t & 63, wv = t >> 6;
#pragma unroll
    for (int off = 1; off < 64; off <<= 1) {
        int y = __shfl_up(x, off, 64);
        if (lane >= off) x += y;
    }
    __shared__ int wsum[4];
    __shared__ int wpre[4];
    if (lane == 63) wsum[wv] = x;
    __syncthreads();
    if (t == 0) {
        int s = 0;
        for (int i = 0; i < 4; ++i) { wpre[i] = s; s += wsum[i]; }
    }
    __syncthreads();
    if (t < NBLK) bsum[seg * NBLK + t] = wpre[wv] + x - v;  // exclusive
}

// ---------------- scanC: final exclusive scan, write rp + pos ----------------
__global__ __launch_bounds__(256) void scanC(const int* __restrict__ deg0,
                                             const int* __restrict__ deg1,
                                             const int* __restrict__ bsum,
                                             int* __restrict__ rp0, int* __restrict__ pos0,
                                             int* __restrict__ rp1, int* __restrict__ pos1) {
    int which = blockIdx.x >= NBLK;
    const int* deg = which ? deg1 : deg0;
    int* rp  = which ? rp1  : rp0;
    int* pos = which ? pos1 : pos0;
    int blk = blockIdx.x - which * NBLK;
    int base = blk * 512 + threadIdx.x * 2;
    int d0 = base < NN ? deg[base] : 0;
    int d1 = base + 1 < NN ? deg[base + 1] : 0;
    int s = d0 + d1;
    int x = s;
    int lane = threadIdx.x & 63, wv = threadIdx.x >> 6;
#pragma unroll
    for (int off = 1; off < 64; off <<= 1) {
        int y = __shfl_up(x, off, 64);
        if (lane >= off) x += y;
    }
    __shared__ int wsum[4];
    __shared__ int wpre[4];
    if (lane == 63) wsum[wv] = x;
    __syncthreads();
    if (threadIdx.x == 0) {
        int ss = 0;
        for (int i = 0; i < 4; ++i) { wpre[i] = ss; ss += wsum[i]; }
    }
    __syncthreads();
    int excl = bsum[blockIdx.x] + wpre[wv] + x - s;
    if (base < NN)     { rp[base] = excl;           pos[base] = excl; }
    if (base + 1 < NN) { rp[base + 1] = excl + d0;  pos[base + 1] = excl + d0; }
    if (blk == 0 && threadIdx.x == 0) rp[NN] = EE;
}

// ---------------- scatter2: both edge lists into CSR order ----------------
__global__ void scatter2(const int* __restrict__ ei0, const float* __restrict__ ew0,
                         int* __restrict__ pos0, int2* __restrict__ ecsr0,
                         const int* __restrict__ ei1, const float* __restrict__ ew1,
                         int* __restrict__ pos1, int2* __restrict__ ecsr1) {
    int which = blockIdx.x >= 2048;
    const int* ei = which ? ei1 : ei0;
    const float* ew = which ? ew1 : ew0;
    int* pos = which ? pos1 : pos0;
    int2* ecsr = which ? ecsr1 : ecsr0;
    long i = (long)(blockIdx.x - which * 2048) * blockDim.x + threadIdx.x;
    long stride = 2048L * blockDim.x;
    for (; i < EE; i += stride) {
        int dst = ei[EE + i];
        int k = atomicAdd(&pos[dst], 1);
        ecsr[k] = make_int2(ei[i], __float_as_int(ew[i]));
    }
}

// ---------------- prew: WU = W1_2@U2, WV = W1_2@V2 (16x64 each) ----------------
__global__ __launch_bounds__(256) void prew(const float* __restrict__ W1_2,
                                            const float* __restrict__ U2,
                                            const float* __restrict__ V2,
                                            float* __restrict__ WU,
                                            float* __restrict__ WV) {
    int t = threadIdx.x;
    for (int i = t; i < 1024; i += 256) {
        int k = i >> 6, j = i & 63;
        float su = 0.f, sv = 0.f;
        for (int m = 0; m < 64; ++m) {
            float wm = W1_2[k * 64 + m];
            su += wm * U2[m * 64 + j];
            sv += wm * V2[m * 64 + j];
        }
        WU[i] = su;
        WV[i] = sv;
    }
}

// ---------------- k1: x1 = X@W1_1 (wave per node), fp32 + bf16 copies ----------------
__global__ __launch_bounds__(256) void k1(const float* __restrict__ X,
                                          const float* __restrict__ W1,
                                          float* __restrict__ x1,
                                          ushort* __restrict__ x1g) {
    __shared__ float Ws[128 * 16];
    __shared__ float Xs[4][4][132];  // wave, b, c (+4 pad)
    int t = threadIdx.x;
    for (int i = t; i < 2048; i += 256) Ws[i] = W1[i];
    int w = t >> 6, lane = t & 63;
    int n = blockIdx.x * 4 + w;
    for (int bb = 0; bb < 2; ++bb) {
        int b = bb * 2 + (lane >> 5);
        int c4 = (lane & 31) * 4;
        float4 v = *reinterpret_cast<const float4*>(&X[((long)b * NN + n) * 128 + c4]);
        *reinterpret_cast<float4*>(&Xs[w][b][c4]) = v;
    }
    __syncthreads();
    int b = lane >> 4, h = lane & 15;
    float acc = 0.f;
#pragma unroll 8
    for (int c = 0; c < 128; ++c) acc += Xs[w][b][c] * Ws[c * 16 + h];
    x1[(long)n * 64 + lane] = acc;
    x1g[(long)n * 64 + lane] = f2bf(acc);
}

// ---------------- k3: layer1 gather+epilogue -> h1 fp32 + h1g bf16 ----------------
__global__ __launch_bounds__(256) void k3(const float* __restrict__ x1,
                                          const ushort* __restrict__ x1g,
                                          const int2* __restrict__ ecsr0,
                                          const int* __restrict__ rp0,
                                          const float* __restrict__ W2_1,
                                          const float* __restrict__ U1,
                                          const float* __restrict__ V1,
                                          float* __restrict__ h1out,
                                          ushort* __restrict__ h1g) {
    __shared__ float U1s[256];
    __shared__ float V1s[256];
    __shared__ float W21s[16];
    __shared__ float x1s[4][64];
    __shared__ float aggs[4][64];
    int t = threadIdx.x;
    U1s[t] = U1[t];
    V1s[t] = V1[t];
    if (t < 16) W21s[t] = W2_1[t];
    int w = t >> 6, lane = t & 63;
    int n = blockIdx.x * 4 + w;
    __syncthreads();
    float xr = x1[(long)n * 64 + lane];
    int start = rp0[n], end = rp0[n + 1];
    float acc = 0.f;
    for (int e = start; e < end; e += 16) {
        int2 r[16];
#pragma unroll
        for (int i = 0; i < 16; ++i) r[i] = ecsr0[e + i];  // memory-safe (global pad)
        float v[16];
#pragma unroll
        for (int i = 0; i < 16; ++i) v[i] = bf2f(x1g[(long)r[i].x * 64 + lane]);
#pragma unroll
        for (int i = 0; i < 16; ++i) {
            float wm = (e + i < end) ? __int_as_float(r[i].y) : 0.f;  // mask tail
            acc += wm * v[i];
        }
    }
    x1s[w][lane] = xr;
    aggs[w][lane] = acc;
    int b = lane >> 4, h = lane & 15;
    float av = 0.f, xu = 0.f;
#pragma unroll
    for (int k = 0; k < 16; ++k) {
        av += aggs[w][b * 16 + k] * V1s[k * 16 + h];
        xu += x1s[w][b * 16 + k] * U1s[k * 16 + h];
    }
    float c = fmaxf((float)(end - start), 1.f);
    float a = xu + W21s[h] * av / c;
    float s = a, s2 = a * a;
#pragma unroll
    for (int off = 32; off >= 1; off >>= 1) {
        s += __shfl_xor(s, off, 64);
        s2 += __shfl_xor(s2, off, 64);
    }
    float mean = s * (1.f / 64.f);
    float var = s2 * (1.f / 64.f) - mean * mean;
    float norm = (a - mean) * rsqrtf(var + EPS);
    float hv = xr + fmaxf(norm, 0.f);
    h1out[(long)n * 64 + lane] = hv;
    h1g[(long)n * 64 + lane] = f2bf(hv);
}

// ---------------- k5: layer2 gather(h1g)+epilogue -> out ----------------
__global__ __launch_bounds__(256) void k5(const float* __restrict__ h1,
                                          const ushort* __restrict__ h1g,
                                          const int2* __restrict__ ecsr1,
                                          const int* __restrict__ rp1,
                                          const float* __restrict__ W2_2,
                                          const float* __restrict__ W1_2,
                                          const float* __restrict__ WU,
                                          const float* __restrict__ WV,
                                          float* __restrict__ out) {
    __shared__ float W12s[1024];
    __shared__ float WUs[1024];
    __shared__ float WVs[1024];
    __shared__ float W22s[64];
    __shared__ float h1s[4][64];
    __shared__ float aggs[4][64];
    int t = threadIdx.x;
    for (int i = t; i < 1024; i += 256) {
        W12s[i] = W1_2[i];
        WUs[i] = WU[i];
        WVs[i] = WV[i];
    }
    if (t < 64) W22s[t] = W2_2[t];
    int w = t >> 6, lane = t & 63;
    int n = blockIdx.x * 4 + w;
    __syncthreads();
    float hv = h1[(long)n * 64 + lane];
    int start = rp1[n], end = rp1[n + 1];
    float acc = 0.f;
    for (int e = start; e < end; e += 16) {
        int2 r[16];
#pragma unroll
        for (int i = 0; i < 16; ++i) r[i] = ecsr1[e + i];  // memory-safe (global pad)
        float v[16];
#pragma unroll
        for (int i = 0; i < 16; ++i) v[i] = bf2f(h1g[(long)r[i].x * 64 + lane]);
#pragma unroll
        for (int i = 0; i < 16; ++i) {
            float wm = (e + i < end) ? __int_as_float(r[i].y) : 0.f;  // mask tail
            acc += wm * v[i];
        }
    }
    h1s[w][lane] = hv;
    aggs[w][lane] = acc;
    float c = fmaxf((float)(end - start), 1.f);
    float x2b[4], ab[4];
    float s = 0.f, s2 = 0.f;
#pragma unroll
    for (int b = 0; b < 4; ++b) {
        float x2 = 0.f, xu = 0.f, av = 0.f;
#pragma unroll
        for (int k = 0; k < 16; ++k) {
            float hk = h1s[w][b * 16 + k];
            float gk = aggs[w][b * 16 + k];
            x2 += hk * W12s[k * 64 + lane];
            xu += hk * WUs[k * 64 + lane];
            av += gk * WVs[k * 64 + lane];
        }
        float a = xu + W22s[lane] * av / c;
        x2b[b] = x2;
        ab[b] = a;
        s += a;
        s2 += a * a;
    }
#pragma unroll
    for (int off = 32; off >= 1; off >>= 1) {
        s += __shfl_xor(s, off, 64);
        s2 += __shfl_xor(s2, off, 64);
    }
    float mean = s * (1.f / 256.f);
    float var = s2 * (1.f / 256.f) - mean * mean;
    float rs = rsqrtf(var + EPS);
#pragma unroll
    for (int b = 0; b < 4; ++b) {
        float norm = (ab[b] - mean) * rs;
        out[((long)b * NN + n) * 64 + lane] = x2b[b] + fmaxf(norm, 0.f);
    }
}

extern "C" void kernel_launch(void* const* d_in, const int* in_sizes, int n_in,
                              void* d_out, int out_size, void* d_ws, size_t ws_size,
                              hipStream_t stream) {
    const float* X    = (const float*)d_in[0];
    const int*   ei0  = (const int*)d_in[1];
    const float* ew0  = (const float*)d_in[2];
    const int*   ei1  = (const int*)d_in[3];
    const float* ew1  = (const float*)d_in[4];
    const float* W1_1 = (const float*)d_in[8];
    const float* W2_1 = (const float*)d_in[9];
    const float* U1   = (const float*)d_in[10];
    const float* V1   = (const float*)d_in[11];
    const float* W1_2 = (const float*)d_in[12];
    const float* W2_2 = (const float*)d_in[13];
    const float* U2   = (const float*)d_in[14];
    const float* V2   = (const float*)d_in[15];
    float* out = (float*)d_out;
    char* ws = (char*)d_ws;

    const long MB = 1000000L;
    float*  x1   = (float*)(ws + 0L);             // 25.6 MB
    float*  h1   = (float*)(ws + 26 * MB);        // 25.6 MB
    int*    deg0 = (int*)(ws + 52 * MB);          // 400 KB
    int*    deg1 = (int*)(ws + 52 * MB + 400000L);
    int*    bsum = (int*)(ws + 52 * MB + 800000L); // 392 ints
    int*    rp0  = (int*)(ws + 53 * MB);
    int*    pos0 = (int*)(ws + 54 * MB);
    int*    rp1  = (int*)(ws + 55 * MB);
    int*    pos1 = (int*)(ws + 56 * MB);
    int2*   ecsr0 = (int2*)(ws + 57 * MB);        // 12.8 MB + 128 B pad
    int2*   ecsr1 = (int2*)(ws + 70 * MB);        // 12.8 MB + 128 B pad
    float*  WU   = (float*)(ws + 83 * MB);        // 4 KB
    float*  WV   = (float*)(ws + 83 * MB + 4096);
    ushort* x1g  = (ushort*)(ws + 84 * MB);       // 12.8 MB
    ushort* h1g  = (ushort*)(ws + 97 * MB);       // 12.8 MB (ends 109.8 MB)

    fill0<<<196, 256, 0, stream>>>((float4*)deg0, 800000L / 16);
    hist<<<2048, 256, 0, stream>>>(ei0, ei1, deg0, deg1, ecsr0, ecsr1);
    scanA<<<2 * NBLK, 256, 0, stream>>>(deg0, deg1, bsum);
    scanB<<<2, 256, 0, stream>>>(bsum);
    scanC<<<2 * NBLK, 256, 0, stream>>>(deg0, deg1, bsum, rp0, pos0, rp1, pos1);
    scatter2<<<4096, 256, 0, stream>>>(ei0, ew0, pos0, ecsr0, ei1, ew1, pos1, ecsr1);
    prew<<<1, 256, 0, stream>>>(W1_2, U2, V2, WU, WV);
    k1<<<25000, 256, 0, stream>>>(X, W1_1, x1, x1g);
    k3<<<25000, 256, 0, stream>>>(x1, x1g, ecsr0, rp0, W2_1, U1, V1, h1, h1g);
    k5<<<25000, 256, 0, stream>>>(h1, h1g, ecsr1, rp1, W2_2, W1_2, WU, WV, out);
}